// Round 3
// baseline (133.993 us; speedup 1.0000x reference)
//
#include <hip/hip_runtime.h>

#define NB 16
#define S_TOK 577
#define SP 576
#define DIM 768
#define NC 256
#define NCLS 1000
#define TK 16

// ---------------- Kernel A: qk[bl,c,s] = sum_d q[b0+bl,s+1,d] * cw[c,d] ----
// f32 GEMM, 64(s) x 64(c) tile, BK=32, LDS k-major for float4 reads.
// Writes into a SLICE-LOCAL qk buffer (bl = blockIdx.z).
__global__ __launch_bounds__(256) void qk_gemm(const float* __restrict__ q,
                                               const float* __restrict__ cw,
                                               float* __restrict__ qk, int b0) {
  const int bl = blockIdx.z;
  const int b = b0 + bl;
  const int s0 = blockIdx.x * 64;
  const int c0 = blockIdx.y * 64;
  __shared__ float As[32][68];
  __shared__ float Bs[32][68];
  const int tid = threadIdx.x;
  const int row = tid >> 3;
  const int k4 = (tid & 7) << 2;
  const int sx = (tid & 15) << 2;
  const int cy = (tid >> 4) << 2;
  float acc[4][4];
#pragma unroll
  for (int i = 0; i < 4; i++)
#pragma unroll
    for (int j = 0; j < 4; j++) acc[i][j] = 0.f;

  const float* qb = q + ((size_t)b * S_TOK + 1) * DIM;

  for (int k0 = 0; k0 < DIM; k0 += 32) {
    float4 a0 = *(const float4*)(qb + (size_t)(s0 + row) * DIM + k0 + k4);
    float4 a1 = *(const float4*)(qb + (size_t)(s0 + row + 32) * DIM + k0 + k4);
    float4 b0v = *(const float4*)(cw + (size_t)(c0 + row) * DIM + k0 + k4);
    float4 b1v = *(const float4*)(cw + (size_t)(c0 + row + 32) * DIM + k0 + k4);
    __syncthreads();
    As[k4 + 0][row] = a0.x; As[k4 + 1][row] = a0.y;
    As[k4 + 2][row] = a0.z; As[k4 + 3][row] = a0.w;
    As[k4 + 0][row + 32] = a1.x; As[k4 + 1][row + 32] = a1.y;
    As[k4 + 2][row + 32] = a1.z; As[k4 + 3][row + 32] = a1.w;
    Bs[k4 + 0][row] = b0v.x; Bs[k4 + 1][row] = b0v.y;
    Bs[k4 + 2][row] = b0v.z; Bs[k4 + 3][row] = b0v.w;
    Bs[k4 + 0][row + 32] = b1v.x; Bs[k4 + 1][row + 32] = b1v.y;
    Bs[k4 + 2][row + 32] = b1v.z; Bs[k4 + 3][row + 32] = b1v.w;
    __syncthreads();
#pragma unroll
    for (int kk = 0; kk < 32; kk++) {
      float4 av = *(const float4*)&As[kk][sx];
      float4 bv = *(const float4*)&Bs[kk][cy];
      float a_[4] = {av.x, av.y, av.z, av.w};
      float b_[4] = {bv.x, bv.y, bv.z, bv.w};
#pragma unroll
      for (int i = 0; i < 4; i++)
#pragma unroll
        for (int j = 0; j < 4; j++) acc[i][j] = fmaf(b_[i], a_[j], acc[i][j]);
    }
  }
#pragma unroll
  for (int i = 0; i < 4; i++) {
    float4 o = make_float4(acc[i][0], acc[i][1], acc[i][2], acc[i][3]);
    *(float4*)(qk + (size_t)(bl * NC + c0 + cy + i) * SP + s0 + sx) = o;
  }
}

// ---------------- Kernel B: top-16 + softmax -> dense score/idx (no atomics)
__global__ __launch_bounds__(256) void topk_store(const float* __restrict__ qk,
                                                  float* __restrict__ score,
                                                  int* __restrict__ sidx, int b0) {
  const int lane = threadIdx.x & 63;
  const int wid = threadIdx.x >> 6;
  const int rcl = blockIdx.x * 4 + wid;   // slice-local (bl*NC + c)
  const int bl = rcl >> 8;
  const int c = rcl & 255;
  const float* rowp = qk + (size_t)rcl * SP;
  float v[9];
#pragma unroll
  for (int j = 0; j < 9; j++) v[j] = rowp[lane + 64 * j];

  float vals[TK];
  int idxs[TK];
#pragma unroll
  for (int t = 0; t < TK; t++) {
    float bv = -1e30f;
    int bj = 0;
#pragma unroll
    for (int j = 0; j < 9; j++)
      if (v[j] > bv) { bv = v[j]; bj = j; }
    int bs = lane + 64 * bj;
#pragma unroll
    for (int off = 32; off >= 1; off >>= 1) {
      float ov = __shfl_xor(bv, off);
      int os = __shfl_xor(bs, off);
      if (ov > bv || (ov == bv && os < bs)) { bv = ov; bs = os; }
    }
    vals[t] = bv;
    idxs[t] = bs;
    const int clr_j = bs >> 6;
    const int clr_lane = bs & 63;
#pragma unroll
    for (int j = 0; j < 9; j++)
      if (j == clr_j && clr_lane == lane) v[j] = -1e30f;
  }
  float m = vals[0];
  float sum = 0.f;
#pragma unroll
  for (int t = 0; t < TK; t++) sum += expf(vals[t] - m);
  if (lane == 0) {
    const float inv = 1.f / (sum * (float)NC);
    const size_t base = ((size_t)(b0 + bl) * NC + c) * TK;
#pragma unroll
    for (int t = 0; t < TK; t++) {
      score[base + t] = expf(vals[t] - m) * inv;
      sidx[base + t] = idxs[t];
    }
  }
}

// ---------------- Kernel C: W[b,s] via LDS scatter (self-zeroing) ----------
__global__ __launch_bounds__(256) void w_build(const float* __restrict__ score,
                                               const int* __restrict__ sidx,
                                               float* __restrict__ W) {
  const int b = blockIdx.x;
  __shared__ float Ws[SP];
  for (int i = threadIdx.x; i < SP; i += 256) Ws[i] = 0.f;
  __syncthreads();
  const size_t base = (size_t)b * NC * TK;
  for (int i = threadIdx.x; i < NC * TK; i += 256)
    atomicAdd(&Ws[sidx[base + i]], score[base + i]);
  __syncthreads();
  for (int i = threadIdx.x; i < SP; i += 256) W[b * SP + i] = Ws[i];
}

// ---------------- Kernel D: h[b,d] = relu( sum_s W[b,s] * q[b,s+1,d] ) ------
__global__ __launch_bounds__(256) void h_compute(const float* __restrict__ q,
                                                 const float* __restrict__ W,
                                                 float* __restrict__ h) {
  const int b = blockIdx.y;
  const int d = blockIdx.x * 256 + threadIdx.x;
  __shared__ float Ws[SP];
  for (int i = threadIdx.x; i < SP; i += 256) Ws[i] = W[b * SP + i];
  __syncthreads();
  const float* qb = q + ((size_t)b * S_TOK + 1) * DIM + d;
  float acc = 0.f;
#pragma unroll 8
  for (int s = 0; s < SP; s++) acc = fmaf(Ws[s], qb[(size_t)s * DIM], acc);
  h[b * DIM + d] = fmaxf(acc, 0.f);
}

// ---------------- Kernel E: y[b,n] = relu_h[b,:] . cls_w[n,:] + cls_b[n] ----
__global__ __launch_bounds__(256) void cls_head(const float* __restrict__ h,
                                                const float* __restrict__ cw,
                                                const float* __restrict__ cb,
                                                float* __restrict__ y) {
  __shared__ float hs[NB * DIM];
  for (int i = threadIdx.x; i < NB * DIM; i += 256) hs[i] = h[i];
  __syncthreads();
  const int lane = threadIdx.x & 63;
  const int n = blockIdx.x * 4 + (threadIdx.x >> 6);
  float wr[12];
#pragma unroll
  for (int j = 0; j < 12; j++) wr[j] = cw[(size_t)n * DIM + lane + 64 * j];
  const float bias = cb[n];
  for (int bb = 0; bb < NB; bb++) {
    float dot = 0.f;
#pragma unroll
    for (int j = 0; j < 12; j++)
      dot = fmaf(wr[j], hs[bb * DIM + lane + 64 * j], dot);
#pragma unroll
    for (int off = 32; off >= 1; off >>= 1) dot += __shfl_xor(dot, off);
    if (lane == 0) y[bb * NCLS + n] = dot + bias;
  }
}

extern "C" void kernel_launch(void* const* d_in, const int* in_sizes, int n_in,
                              void* d_out, int out_size, void* d_ws, size_t ws_size,
                              hipStream_t stream) {
  const float* q = (const float*)d_in[0];
  const float* cw = (const float*)d_in[1];
  const float* clsw = (const float*)d_in[2];
  const float* clsb = (const float*)d_in[3];
  float* out = (float*)d_out;

  // Fixed aux region first, slice-reused qk buffer after.
  float* score = (float*)d_ws;                       // NB*NC*TK f32 (256KB)
  int* sidx = (int*)(score + (size_t)NB * NC * TK);  // NB*NC*TK i32 (256KB)
  float* W = (float*)(sidx + (size_t)NB * NC * TK);  // NB*SP
  float* h = W + (size_t)NB * SP;                    // NB*DIM
  float* qk = h + (size_t)NB * DIM;                  // slice buffer
  const size_t aux_bytes = (size_t)((char*)qk - (char*)d_ws);

  // Largest power-of-2 b-per-slice that fits the actual workspace.
  int bper = NB;
  while (bper > 1 &&
         aux_bytes + (size_t)bper * NC * SP * sizeof(float) > ws_size)
    bper >>= 1;

  for (int b0 = 0; b0 < NB; b0 += bper) {
    qk_gemm<<<dim3(9, 4, bper), 256, 0, stream>>>(q, cw, qk, b0);
    topk_store<<<(bper * NC) / 4, 256, 0, stream>>>(qk, score, sidx, b0);
  }
  w_build<<<NB, 256, 0, stream>>>(score, sidx, W);
  h_compute<<<dim3(3, NB), 256, 0, stream>>>(q, W, h);
  cls_head<<<NCLS / 4, 256, 0, stream>>>(h, clsw, clsb, out);
}

// Round 4
// 76.659 us; speedup vs baseline: 1.7479x; 1.7479x over previous
//
#include <hip/hip_runtime.h>

#define NB 16
#define S_TOK 577
#define SP 576
#define DIM 768
#define NC 256
#define NCLS 1000
#define TK 16
#define HCH 6
#define HCHS 96  // 576/6

typedef __attribute__((ext_vector_type(8))) __bf16 bf16x8;
typedef __attribute__((ext_vector_type(4))) float f32x4;

// Split one 8-float chunk into hi/lo bf16 (RNE both steps).
__device__ __forceinline__ void cvt_split(const float4 a, const float4 b,
                                          bf16x8& hi, bf16x8& lo) {
  float v[8] = {a.x, a.y, a.z, a.w, b.x, b.y, b.z, b.w};
#pragma unroll
  for (int i = 0; i < 8; i++) {
    __bf16 h = (__bf16)v[i];
    hi[i] = h;
    lo[i] = (__bf16)(v[i] - (float)h);
  }
}

// Read one 16B MFMA fragment (row r, k-chunk kc) from a swizzled LDS tile.
__device__ __forceinline__ bf16x8 frag_ld(const char* base, int r, int kc) {
  return *(const bf16x8*)(base + ((r * 4 + (kc ^ (r & 3))) << 4));
}

// ---------------- Kernel A: qk[bl,c,s] = sum_d cw[c,d] * q[b,s+1,d] --------
// bf16 3-pass split MFMA; 64(c)x64(s) block tile, 4 waves of 32x32.
__global__ __launch_bounds__(256) void qk_gemm_mfma(const float* __restrict__ q,
                                                    const float* __restrict__ cw,
                                                    float* __restrict__ qk, int b0) {
  const int bl = blockIdx.z;
  const int s0 = blockIdx.x * 64;
  const int c0 = blockIdx.y * 64;
  __shared__ __align__(16) char sAH[4096], sAL[4096], sBH[4096], sBL[4096];

  const int tid = threadIdx.x;
  const int lane = tid & 63;
  const int wid = tid >> 6;
  const int wc = (wid >> 1) << 5;  // wave c-offset (0/32)
  const int wsv = (wid & 1) << 5;  // wave s-offset (0/32)
  const int fr = lane & 15;
  const int kq = lane >> 4;  // k-chunk 0..3

  // staging coords: thread -> (row 0..63, 8-float chunk 0..3), swizzled slot
  const int r = tid >> 2;
  const int ck = tid & 3;
  const int wslot = (r * 4 + (ck ^ (r & 3))) << 4;

  const float* qb = q + ((size_t)(b0 + bl) * S_TOK + 1) * DIM;
  const float* arow = cw + (size_t)(c0 + r) * DIM + ck * 8;
  const float* brow = qb + (size_t)(s0 + r) * DIM + ck * 8;

  f32x4 zero = {0.f, 0.f, 0.f, 0.f};
  f32x4 acc[2][2];
#pragma unroll
  for (int i = 0; i < 2; i++)
#pragma unroll
    for (int j = 0; j < 2; j++) acc[i][j] = zero;

  for (int k0 = 0; k0 < DIM; k0 += 32) {
    float4 a0 = *(const float4*)(arow + k0);
    float4 a1 = *(const float4*)(arow + k0 + 4);
    float4 b0v = *(const float4*)(brow + k0);
    float4 b1v = *(const float4*)(brow + k0 + 4);
    __syncthreads();  // previous iter's fragment readers done
    bf16x8 h, l;
    cvt_split(a0, a1, h, l);
    *(bf16x8*)(sAH + wslot) = h;
    *(bf16x8*)(sAL + wslot) = l;
    cvt_split(b0v, b1v, h, l);
    *(bf16x8*)(sBH + wslot) = h;
    *(bf16x8*)(sBL + wslot) = l;
    __syncthreads();
    bf16x8 a0h = frag_ld(sAH, wc + fr, kq);
    bf16x8 a0l = frag_ld(sAL, wc + fr, kq);
    bf16x8 a1h = frag_ld(sAH, wc + 16 + fr, kq);
    bf16x8 a1l = frag_ld(sAL, wc + 16 + fr, kq);
    bf16x8 b0h = frag_ld(sBH, wsv + fr, kq);
    bf16x8 b0l = frag_ld(sBL, wsv + fr, kq);
    bf16x8 b1h = frag_ld(sBH, wsv + 16 + fr, kq);
    bf16x8 b1l = frag_ld(sBL, wsv + 16 + fr, kq);
#define MF(A, B, C) C = __builtin_amdgcn_mfma_f32_16x16x32_bf16(A, B, C, 0, 0, 0)
    MF(a0h, b0h, acc[0][0]); MF(a0h, b0l, acc[0][0]); MF(a0l, b0h, acc[0][0]);
    MF(a0h, b1h, acc[0][1]); MF(a0h, b1l, acc[0][1]); MF(a0l, b1h, acc[0][1]);
    MF(a1h, b0h, acc[1][0]); MF(a1h, b0l, acc[1][0]); MF(a1l, b0h, acc[1][0]);
    MF(a1h, b1h, acc[1][1]); MF(a1h, b1l, acc[1][1]); MF(a1l, b1h, acc[1][1]);
#undef MF
  }
  // C/D layout (m89-verified): col = lane&15, row = (lane>>4)*4 + reg
  float* obase = qk + (size_t)bl * NC * SP;
#pragma unroll
  for (int i = 0; i < 2; i++)
#pragma unroll
    for (int j = 0; j < 2; j++)
#pragma unroll
      for (int rr = 0; rr < 4; rr++) {
        const int row = c0 + wc + i * 16 + kq * 4 + rr;
        const int col = s0 + wsv + j * 16 + fr;
        obase[(size_t)row * SP + col] = acc[i][j][rr];
      }
}

// ---------------- Kernel B: top-16 + softmax -> dense score/idx ------------
__global__ __launch_bounds__(256) void topk_store(const float* __restrict__ qk,
                                                  float* __restrict__ score,
                                                  int* __restrict__ sidx, int b0) {
  const int lane = threadIdx.x & 63;
  const int wid = threadIdx.x >> 6;
  const int rcl = blockIdx.x * 4 + wid;
  const int bl = rcl >> 8;
  const int c = rcl & 255;
  const float* rowp = qk + (size_t)rcl * SP;
  float v[9];
#pragma unroll
  for (int j = 0; j < 9; j++) v[j] = rowp[lane + 64 * j];

  float vals[TK];
  int idxs[TK];
#pragma unroll
  for (int t = 0; t < TK; t++) {
    float bv = -1e30f;
    int bj = 0;
#pragma unroll
    for (int j = 0; j < 9; j++)
      if (v[j] > bv) { bv = v[j]; bj = j; }
    int bs = lane + 64 * bj;
#pragma unroll
    for (int off = 32; off >= 1; off >>= 1) {
      float ov = __shfl_xor(bv, off);
      int os = __shfl_xor(bs, off);
      if (ov > bv || (ov == bv && os < bs)) { bv = ov; bs = os; }
    }
    vals[t] = bv;
    idxs[t] = bs;
    const int clr_j = bs >> 6;
    const int clr_lane = bs & 63;
#pragma unroll
    for (int j = 0; j < 9; j++)
      if (j == clr_j && clr_lane == lane) v[j] = -1e30f;
  }
  float m = vals[0];
  float sum = 0.f;
#pragma unroll
  for (int t = 0; t < TK; t++) sum += expf(vals[t] - m);
  if (lane == 0) {
    const float inv = 1.f / (sum * (float)NC);
    const size_t base = ((size_t)(b0 + bl) * NC + c) * TK;
#pragma unroll
    for (int t = 0; t < TK; t++) {
      score[base + t] = expf(vals[t] - m) * inv;
      sidx[base + t] = idxs[t];
    }
  }
}

// ---------------- Kernel C: W[b,s] via LDS scatter (self-zeroing) ----------
__global__ __launch_bounds__(256) void w_build(const float* __restrict__ score,
                                               const int* __restrict__ sidx,
                                               float* __restrict__ W) {
  const int b = blockIdx.x;
  __shared__ float Ws[SP];
  for (int i = threadIdx.x; i < SP; i += 256) Ws[i] = 0.f;
  __syncthreads();
  const size_t base = (size_t)b * NC * TK;
  for (int i = threadIdx.x; i < NC * TK; i += 256)
    atomicAdd(&Ws[sidx[base + i]], score[base + i]);
  __syncthreads();
  for (int i = threadIdx.x; i < SP; i += 256) W[b * SP + i] = Ws[i];
}

// ---------------- Kernel D: hpart[ch,b,d] = sum_{s in chunk} W*q ------------
__global__ __launch_bounds__(256) void h_partial(const float* __restrict__ q,
                                                 const float* __restrict__ W,
                                                 float* __restrict__ hpart) {
  const int b = blockIdx.y;
  const int ch = blockIdx.z;
  const int d = blockIdx.x * 256 + threadIdx.x;
  __shared__ float Ws[HCHS];
  if (threadIdx.x < HCHS) Ws[threadIdx.x] = W[b * SP + ch * HCHS + threadIdx.x];
  __syncthreads();
  const float* qb = q + ((size_t)b * S_TOK + 1 + ch * HCHS) * DIM + d;
  float acc = 0.f;
#pragma unroll 8
  for (int s = 0; s < HCHS; s++) acc = fmaf(Ws[s], qb[(size_t)s * DIM], acc);
  hpart[((size_t)ch * NB + b) * DIM + d] = acc;
}

// ---------------- Kernel E: y = relu(sum_ch hpart) @ cls_w^T + cls_b --------
__global__ __launch_bounds__(256) void cls_head(const float* __restrict__ hp,
                                                const float* __restrict__ cw,
                                                const float* __restrict__ cb,
                                                float* __restrict__ y) {
  __shared__ float hs[NB * DIM];
  for (int i = threadIdx.x; i < NB * DIM; i += 256) {
    float s = 0.f;
#pragma unroll
    for (int ch = 0; ch < HCH; ch++) s += hp[(size_t)ch * NB * DIM + i];
    hs[i] = fmaxf(s, 0.f);
  }
  __syncthreads();
  const int lane = threadIdx.x & 63;
  const int n = blockIdx.x * 4 + (threadIdx.x >> 6);
  float wr[12];
#pragma unroll
  for (int j = 0; j < 12; j++) wr[j] = cw[(size_t)n * DIM + lane + 64 * j];
  const float bias = cb[n];
  for (int bb = 0; bb < NB; bb++) {
    float dot = 0.f;
#pragma unroll
    for (int j = 0; j < 12; j++)
      dot = fmaf(wr[j], hs[bb * DIM + lane + 64 * j], dot);
#pragma unroll
    for (int off = 32; off >= 1; off >>= 1) dot += __shfl_xor(dot, off);
    if (lane == 0) y[bb * NCLS + n] = dot + bias;
  }
}

extern "C" void kernel_launch(void* const* d_in, const int* in_sizes, int n_in,
                              void* d_out, int out_size, void* d_ws, size_t ws_size,
                              hipStream_t stream) {
  const float* q = (const float*)d_in[0];
  const float* cw = (const float*)d_in[1];
  const float* clsw = (const float*)d_in[2];
  const float* clsb = (const float*)d_in[3];
  float* out = (float*)d_out;

  // Fixed aux region first, slice-reused qk buffer after.
  float* score = (float*)d_ws;                       // NB*NC*TK f32
  int* sidx = (int*)(score + (size_t)NB * NC * TK);  // NB*NC*TK i32
  float* W = (float*)(sidx + (size_t)NB * NC * TK);  // NB*SP
  float* hpart = W + (size_t)NB * SP;                // HCH*NB*DIM
  float* qk = hpart + (size_t)HCH * NB * DIM;        // slice buffer
  const size_t aux_bytes = (size_t)((char*)qk - (char*)d_ws);

  int bper = NB;
  while (bper > 1 &&
         aux_bytes + (size_t)bper * NC * SP * sizeof(float) > ws_size)
    bper >>= 1;

  for (int b0 = 0; b0 < NB; b0 += bper) {
    qk_gemm_mfma<<<dim3(9, 4, bper), 256, 0, stream>>>(q, cw, qk, b0);
    topk_store<<<(bper * NC) / 4, 256, 0, stream>>>(qk, score, sidx, b0);
  }
  w_build<<<NB, 256, 0, stream>>>(score, sidx, W);
  h_partial<<<dim3(3, NB, HCH), 256, 0, stream>>>(q, W, hpart);
  cls_head<<<NCLS / 4, 256, 0, stream>>>(hpart, clsw, clsb, out);
}

// Round 5
// 73.878 us; speedup vs baseline: 1.8137x; 1.0376x over previous
//
#include <hip/hip_runtime.h>

#define NB 16
#define S_TOK 577
#define SP 576
#define DIM 768
#define NC 256
#define NCLS 1000
#define TK 16
#define HCH 6
#define HCHS 96  // 576/6

typedef __attribute__((ext_vector_type(8))) __bf16 bf16x8;
typedef __attribute__((ext_vector_type(4))) float f32x4;

// Split one 8-float chunk into hi/lo bf16 (RNE both steps).
__device__ __forceinline__ void cvt_split(const float4 a, const float4 b,
                                          bf16x8& hi, bf16x8& lo) {
  float v[8] = {a.x, a.y, a.z, a.w, b.x, b.y, b.z, b.w};
#pragma unroll
  for (int i = 0; i < 8; i++) {
    __bf16 h = (__bf16)v[i];
    hi[i] = h;
    lo[i] = (__bf16)(v[i] - (float)h);
  }
}

// Read one 16B MFMA fragment (row r, k-chunk kc) from a swizzled LDS tile.
__device__ __forceinline__ bf16x8 frag_ld(const char* base, int r, int kc) {
  return *(const bf16x8*)(base + ((r * 4 + (kc ^ (r & 3))) << 4));
}

// ---------------- Kernel A: qk[bl,c,s] = sum_d cw[c,d] * q[b,s+1,d] --------
// bf16 3-pass split MFMA; 128(c)x64(s) block tile, 4 waves of 64x32.
// Blocks (0,0,bl) also zero W[b0+bl] for the downstream atomic scatter.
__global__ __launch_bounds__(256) void qk_gemm_mfma(const float* __restrict__ q,
                                                    const float* __restrict__ cw,
                                                    float* __restrict__ qk,
                                                    float* __restrict__ W, int b0) {
  const int bl = blockIdx.z;
  const int s0 = blockIdx.x * 64;
  const int c0 = blockIdx.y * 128;
  __shared__ __align__(16) char sAH[8192], sAL[8192], sBH[4096], sBL[4096];

  if (blockIdx.x == 0 && blockIdx.y == 0) {
    for (int i = threadIdx.x; i < SP; i += 256) W[(b0 + bl) * SP + i] = 0.f;
  }

  const int tid = threadIdx.x;
  const int lane = tid & 63;
  const int wid = tid >> 6;
  const int wc = (wid >> 1) << 6;  // wave c-offset (0/64)
  const int wsv = (wid & 1) << 5;  // wave s-offset (0/32)
  const int fr = lane & 15;
  const int kq = lane >> 4;  // k-chunk 0..3

  // staging coords: A -> 2 chunks/thread, B -> 1 chunk/thread
  const int ra0 = (tid * 2) >> 2, cka0 = (tid * 2) & 3;
  const int ra1 = (tid * 2 + 1) >> 2, cka1 = (tid * 2 + 1) & 3;
  const int rb = tid >> 2, ckb = tid & 3;
  const int slotA0 = (ra0 * 4 + (cka0 ^ (ra0 & 3))) << 4;
  const int slotA1 = (ra1 * 4 + (cka1 ^ (ra1 & 3))) << 4;
  const int slotB = (rb * 4 + (ckb ^ (rb & 3))) << 4;

  const float* qb = q + ((size_t)(b0 + bl) * S_TOK + 1) * DIM;
  const float* arow0 = cw + (size_t)(c0 + ra0) * DIM + cka0 * 8;
  const float* arow1 = cw + (size_t)(c0 + ra1) * DIM + cka1 * 8;
  const float* brow = qb + (size_t)(s0 + rb) * DIM + ckb * 8;

  f32x4 zero = {0.f, 0.f, 0.f, 0.f};
  f32x4 acc[4][2];
#pragma unroll
  for (int i = 0; i < 4; i++)
#pragma unroll
    for (int j = 0; j < 2; j++) acc[i][j] = zero;

  for (int k0 = 0; k0 < DIM; k0 += 32) {
    float4 a00 = *(const float4*)(arow0 + k0);
    float4 a01 = *(const float4*)(arow0 + k0 + 4);
    float4 a10 = *(const float4*)(arow1 + k0);
    float4 a11 = *(const float4*)(arow1 + k0 + 4);
    float4 b0v = *(const float4*)(brow + k0);
    float4 b1v = *(const float4*)(brow + k0 + 4);
    __syncthreads();  // previous iter's fragment readers done
    bf16x8 h, l;
    cvt_split(a00, a01, h, l);
    *(bf16x8*)(sAH + slotA0) = h;
    *(bf16x8*)(sAL + slotA0) = l;
    cvt_split(a10, a11, h, l);
    *(bf16x8*)(sAH + slotA1) = h;
    *(bf16x8*)(sAL + slotA1) = l;
    cvt_split(b0v, b1v, h, l);
    *(bf16x8*)(sBH + slotB) = h;
    *(bf16x8*)(sBL + slotB) = l;
    __syncthreads();
    bf16x8 ah[4], al[4], bh[2], blo[2];
#pragma unroll
    for (int i = 0; i < 4; i++) {
      ah[i] = frag_ld(sAH, wc + i * 16 + fr, kq);
      al[i] = frag_ld(sAL, wc + i * 16 + fr, kq);
    }
#pragma unroll
    for (int j = 0; j < 2; j++) {
      bh[j] = frag_ld(sBH, wsv + j * 16 + fr, kq);
      blo[j] = frag_ld(sBL, wsv + j * 16 + fr, kq);
    }
#define MF(A, B, C) C = __builtin_amdgcn_mfma_f32_16x16x32_bf16(A, B, C, 0, 0, 0)
#pragma unroll
    for (int i = 0; i < 4; i++)
#pragma unroll
      for (int j = 0; j < 2; j++) {
        MF(ah[i], bh[j], acc[i][j]);
        MF(ah[i], blo[j], acc[i][j]);
        MF(al[i], bh[j], acc[i][j]);
      }
#undef MF
  }
  // C/D layout (m89-verified): col(s) = lane&15, row(c) = (lane>>4)*4 + reg
  float* obase = qk + (size_t)bl * NC * SP;
#pragma unroll
  for (int i = 0; i < 4; i++)
#pragma unroll
    for (int j = 0; j < 2; j++)
#pragma unroll
      for (int rr = 0; rr < 4; rr++) {
        const int row = c0 + wc + i * 16 + kq * 4 + rr;
        const int col = s0 + wsv + j * 16 + fr;
        obase[(size_t)row * SP + col] = acc[i][j][rr];
      }
}

// ---------------- Kernel B: top-16 + softmax -> atomic scatter into W ------
__global__ __launch_bounds__(256) void topk_scatter(const float* __restrict__ qk,
                                                    float* __restrict__ W, int b0) {
  const int lane = threadIdx.x & 63;
  const int wid = threadIdx.x >> 6;
  const int rcl = blockIdx.x * 4 + wid;  // slice-local (bl*NC + c)
  const int bl = rcl >> 8;
  const int b = b0 + bl;
  const float* rowp = qk + (size_t)rcl * SP;
  float v[9];
#pragma unroll
  for (int j = 0; j < 9; j++) v[j] = rowp[lane + 64 * j];

  float vals[TK];
  int idxs[TK];
#pragma unroll
  for (int t = 0; t < TK; t++) {
    float bv = -1e30f;
    int bj = 0;
#pragma unroll
    for (int j = 0; j < 9; j++)
      if (v[j] > bv) { bv = v[j]; bj = j; }
    int bs = lane + 64 * bj;
#pragma unroll
    for (int off = 32; off >= 1; off >>= 1) {
      float ov = __shfl_xor(bv, off);
      int os = __shfl_xor(bs, off);
      if (ov > bv || (ov == bv && os < bs)) { bv = ov; bs = os; }
    }
    vals[t] = bv;
    idxs[t] = bs;
    const int clr_j = bs >> 6;
    const int clr_lane = bs & 63;
#pragma unroll
    for (int j = 0; j < 9; j++)
      if (j == clr_j && clr_lane == lane) v[j] = -1e30f;
  }
  float m = vals[0];
  float sum = 0.f;
#pragma unroll
  for (int t = 0; t < TK; t++) sum += expf(vals[t] - m);
  if (lane == 0) {
    const float inv = 1.f / (sum * (float)NC);
#pragma unroll
    for (int t = 0; t < TK; t++)
      atomicAdd(&W[b * SP + idxs[t]], expf(vals[t] - m) * inv);
  }
}

// ---------------- Kernel C: hpart[ch,b,d] = sum_{s in chunk} W*q ------------
__global__ __launch_bounds__(256) void h_partial(const float* __restrict__ q,
                                                 const float* __restrict__ W,
                                                 float* __restrict__ hpart) {
  const int b = blockIdx.y;
  const int ch = blockIdx.z;
  const int d = blockIdx.x * 256 + threadIdx.x;
  __shared__ float Ws[HCHS];
  if (threadIdx.x < HCHS) Ws[threadIdx.x] = W[b * SP + ch * HCHS + threadIdx.x];
  __syncthreads();
  const float* qb = q + ((size_t)b * S_TOK + 1 + ch * HCHS) * DIM + d;
  float acc = 0.f;
#pragma unroll 8
  for (int s = 0; s < HCHS; s++) acc = fmaf(Ws[s], qb[(size_t)s * DIM], acc);
  hpart[((size_t)ch * NB + b) * DIM + d] = acc;
}

// ---------------- Kernel D: y = relu(sum_ch hpart) @ cls_w^T + cls_b --------
__global__ __launch_bounds__(256) void cls_head(const float* __restrict__ hp,
                                                const float* __restrict__ cw,
                                                const float* __restrict__ cb,
                                                float* __restrict__ y) {
  __shared__ float hs[NB * DIM];
  for (int i = threadIdx.x; i < NB * DIM; i += 256) {
    float s = 0.f;
#pragma unroll
    for (int ch = 0; ch < HCH; ch++) s += hp[(size_t)ch * NB * DIM + i];
    hs[i] = fmaxf(s, 0.f);
  }
  __syncthreads();
  const int lane = threadIdx.x & 63;
  const int n = blockIdx.x * 4 + (threadIdx.x >> 6);
  float wr[12];
#pragma unroll
  for (int j = 0; j < 12; j++) wr[j] = cw[(size_t)n * DIM + lane + 64 * j];
  const float bias = cb[n];
  for (int bb = 0; bb < NB; bb++) {
    float dot = 0.f;
#pragma unroll
    for (int j = 0; j < 12; j++)
      dot = fmaf(wr[j], hs[bb * DIM + lane + 64 * j], dot);
#pragma unroll
    for (int off = 32; off >= 1; off >>= 1) dot += __shfl_xor(dot, off);
    if (lane == 0) y[bb * NCLS + n] = dot + bias;
  }
}

extern "C" void kernel_launch(void* const* d_in, const int* in_sizes, int n_in,
                              void* d_out, int out_size, void* d_ws, size_t ws_size,
                              hipStream_t stream) {
  const float* q = (const float*)d_in[0];
  const float* cw = (const float*)d_in[1];
  const float* clsw = (const float*)d_in[2];
  const float* clsb = (const float*)d_in[3];
  float* out = (float*)d_out;

  // Fixed aux region first, slice-reused qk buffer after.
  float* W = (float*)d_ws;                    // NB*SP
  float* hpart = W + (size_t)NB * SP;         // HCH*NB*DIM
  float* qk = hpart + (size_t)HCH * NB * DIM; // slice buffer
  const size_t aux_bytes = (size_t)((char*)qk - (char*)d_ws);

  int bper = NB;
  while (bper > 1 &&
         aux_bytes + (size_t)bper * NC * SP * sizeof(float) > ws_size)
    bper >>= 1;

  for (int b0 = 0; b0 < NB; b0 += bper) {
    qk_gemm_mfma<<<dim3(9, 2, bper), 256, 0, stream>>>(q, cw, qk, W, b0);
    topk_scatter<<<(bper * NC) / 4, 256, 0, stream>>>(qk, W, b0);
  }
  h_partial<<<dim3(3, NB, HCH), 256, 0, stream>>>(q, W, hpart);
  cls_head<<<NCLS / 4, 256, 0, stream>>>(hpart, clsw, clsb, out);
}